// Round 14
// baseline (727.353 us; speedup 1.0000x reference)
//
#include <hip/hip_runtime.h>
#include <cstdint>

typedef __attribute__((ext_vector_type(4))) float f32x4;
typedef __attribute__((ext_vector_type(8))) short bf16x8;
typedef __attribute__((ext_vector_type(4))) short bf16x4;

#define DEV static __device__ __forceinline__

// round-to-nearest-even f32 -> bf16 (bit pattern)
DEV unsigned short f2bf(float f) {
    union { float f; unsigned int u; } v; v.f = f;
    unsigned int u = v.u;
    return (unsigned short)((u + 0x7FFFu + ((u >> 16) & 1u)) >> 16);
}

// async global->LDS 16B per lane; LDS dest = wave-uniform base + lane*16
DEV void async_cp16(const void* g, void* l) {
    __builtin_amdgcn_global_load_lds(
        (const __attribute__((address_space(1))) unsigned int*)g,
        (__attribute__((address_space(3))) unsigned int*)l,
        16, 0, 0);
}

#define BAR __builtin_amdgcn_s_barrier();
#define SCB __builtin_amdgcn_sched_barrier(0);
#define LGKM0 asm volatile("s_waitcnt lgkmcnt(0)");
#define P1 __builtin_amdgcn_s_setprio(1);
#define P0 __builtin_amdgcn_s_setprio(0);
#define VM0 asm volatile("s_waitcnt vmcnt(0)" ::: "memory");
#define VM2 asm volatile("s_waitcnt vmcnt(2)" ::: "memory");
#define VM4 asm volatile("s_waitcnt vmcnt(4)" ::: "memory");

// stage a 128x32 bf16 tile (8KB): 2 x 16B per thread (256 thr); linear LDS
// dest, inverse-swizzled source. Involution for 64B row pitch: slot ^=
// (row>>1)&3 (bank-group G = 4*(row&1) + slot^((row>>1)&3): 2-way = free).
DEV void stage_T32(const unsigned short* __restrict__ g, long kofs,
                   unsigned short* l, int tid, int gp) {
#pragma unroll
    for (int i = 0; i < 2; ++i) {
        int c = i * 256 + tid;
        int row = c >> 2;
        int ss = (c & 3) ^ ((row >> 1) & 3);
        async_cp16(g + (long)row * gp + kofs + ss * 8,
                   l + (i * 256 + (tid & 192)) * 8);
    }
}

// ---------------------------------------------------------------------------
// 128x128 4-wave GEMM core, BK=32, 40KB LDS -> 4 blocks/CU. Each SIMD hosts
// 4 waves from 4 DIFFERENT blocks (independent barrier domains) -> barriers
// never idle a whole SIMD.
// LDS (ushorts): A bufs 0/4096/8192 (triple), B bufs 12288/16384 (double).
// Wave (wr=wv>>1, wc=wv&1) owns C rows [wr*64,+64) x cols [wc*64,+64).
// Per K-tile t: 2 phases, ONE mid-phase barrier each:
//   ph0: {read af x4 + bf01; stage B(t+1) (t>=1); BAR; lgkm0; 8 MFMA}
//   ph1: {read bf23; stage A(t+2); vm-gate; BAR; lgkm0; 8 MFMA}
// WAR ledger (single BAR valid): a stage in phase p follows BAR(p-1); the
// target buffer's last reads precede BAR(p-1) (B(t+1)->pb1: last read
// ph1(t-1) pre-BAR; A(t+2)->pa2: last read ph0(t-1) pre-BAR). MFMA after BAR
// uses registers only. Staging write-back arrives >=200cyc after issue,
// far behind the pre-BAR ds_reads' ~100cyc completion.
// vmcnt ledger (2 loads per stage): gate(ph1(t)): outstanding =
// [A(t+1)2, B(t+1)2, A(t+2)2] -> VM2 drains tile t+1, leaves A(t+2).
// Prologue A0,B0,A1,B1 -> VM4. Tail: t=NT-2 VM0; t=NT-1 no gate.
// ---------------------------------------------------------------------------
template <int NT>
DEV void gemmC(const unsigned short* __restrict__ gA,
               const unsigned short* __restrict__ gB,
               const int gpa, const int gpb, unsigned short* lds,
               f32x4 (&acc)[4][4], const int tid) {
    const int lane = tid & 63;
    const int wv = tid >> 6;
    const int wr = wv >> 1, wc = wv & 1;
    const int lhi = lane >> 4, llo = lane & 15;
    // frag row = base + llo, base % 16 == 0 -> (row>>1)&3 == (llo>>1)&3
    const int sw = (lhi ^ ((llo >> 1) & 3)) << 3;
    const int aoff = (wr * 64 + llo) * 32 + sw;   // + i*512 per 16-row step
    const int boff = (wc * 64 + llo) * 32 + sw;   // + j*512

    unsigned short *pa0 = lds, *pa1 = lds + 4096, *pa2 = lds + 8192;
    unsigned short *pb0 = lds + 12288, *pb1 = lds + 16384;

#define MGJ(J)                                                                \
    _Pragma("unroll") for (int i = 0; i < 4; ++i)                             \
    _Pragma("unroll") for (int jj = 0; jj < 2; ++jj)                          \
        acc[i][(J) + jj] = __builtin_amdgcn_mfma_f32_16x16x32_bf16(           \
            af[i], bf[(J) + jj], acc[i][(J) + jj], 0, 0, 0);

    // prologue: A0,B0,A1,B1 (8 loads); drain A0,B0 (VM4), leave A1,B1
    stage_T32(gA, 0, pa0, tid, gpa);
    stage_T32(gB, 0, pb0, tid, gpb);
    stage_T32(gA, 32, pa1, tid, gpa);
    stage_T32(gB, 32, pb1, tid, gpb);
    VM4
    BAR SCB

    bf16x8 af[4], bf[4];
    for (int t = 0; t < NT; ++t) {
        const bool pf1 = (t + 1 < NT);
        const bool pf2 = (t + 2 < NT);
        // ---- ph0: read A frags + B j0,j1; stage B(t+1); BAR; MFMA --------
#pragma unroll
        for (int i = 0; i < 4; ++i) af[i] = *(const bf16x8*)&pa0[aoff + i * 512];
        bf[0] = *(const bf16x8*)&pb0[boff];
        bf[1] = *(const bf16x8*)&pb0[boff + 512];
        if (t >= 1 && pf1) stage_T32(gB, (long)(t + 1) * 32, pb1, tid, gpb);
        BAR LGKM0 SCB
        P1 MGJ(0) P0
        // ---- ph1: read B j2,j3; stage A(t+2); gate; BAR; MFMA ------------
        bf[2] = *(const bf16x8*)&pb0[boff + 1024];
        bf[3] = *(const bf16x8*)&pb0[boff + 1536];
        if (pf2) stage_T32(gA, (long)(t + 2) * 32, pa2, tid, gpa);
        if (pf1) { if (pf2) { VM2 } else { VM0 } }
        BAR LGKM0 SCB
        P1 MGJ(2) P0
        // rotate buffers
        unsigned short* tp = pa0; pa0 = pa1; pa1 = pa2; pa2 = tp;
        tp = pb0; pb0 = pb1; pb1 = tp;
    }
#undef MGJ
}

// ---------------------------------------------------------------------------
// Kernel 0: weight prep.
//  w12t[n][k]: n even -> bf16(w0[k]*w1[k][n/2]), n odd -> bf16(w0[k]*w2[k][n/2])
//  w3t[j][n] = bf16(w3[n][j])   (1024 x 512, n contiguous)
// ---------------------------------------------------------------------------
__global__ void prep_w(const float* __restrict__ w0, const float* __restrict__ w1,
                       const float* __restrict__ w2, const float* __restrict__ w3,
                       unsigned short* __restrict__ w12t, unsigned short* __restrict__ w3t) {
    int t = blockIdx.x * 256 + threadIdx.x;
    if (t < 1048576) {
        int n = t >> 10, k = t & 1023;
        const float* src = (n & 1) ? w2 : w1;
        w12t[t] = f2bf(w0[k] * src[k * 512 + (n >> 1)]);
    } else {
        int idx = t - 1048576;
        int j = idx >> 9, n = idx & 511;
        w3t[idx] = f2bf(w3[n * 1024 + j]);
    }
}

// ---------------------------------------------------------------------------
// Kernel 0b: RMSNorm fold. xb[row][k] = bf16(x[row][k] * rsqrt(mean(x^2)))
// ---------------------------------------------------------------------------
__global__ __launch_bounds__(256)
void prep_x(const float* __restrict__ x, unsigned short* __restrict__ xb) {
    const int wv = threadIdx.x >> 6, lane = threadIdx.x & 63;
    const int stride = gridDim.x * 4;
    for (int row = blockIdx.x * 4 + wv; row < 131072; row += stride) {
        const float* xr = x + (long)row * 1024;
        f32x4 v[4];
        float s = 0.f;
#pragma unroll
        for (int c = 0; c < 4; ++c) {
            v[c] = *(const f32x4*)(xr + c * 256 + lane * 4);
            s += v[c].x * v[c].x + v[c].y * v[c].y + v[c].z * v[c].z + v[c].w * v[c].w;
        }
#pragma unroll
        for (int off = 32; off > 0; off >>= 1) s += __shfl_xor(s, off, 64);
        float l = rsqrtf(s * (1.0f / 1024.0f));
        unsigned short* xo = xb + (long)row * 1024;
#pragma unroll
        for (int c = 0; c < 4; ++c) {
            bf16x4 b;
            b.x = (short)f2bf(v[c].x * l);
            b.y = (short)f2bf(v[c].y * l);
            b.z = (short)f2bf(v[c].z * l);
            b.w = (short)f2bf(v[c].w * l);
            *(bf16x4*)(xo + c * 256 + lane * 4) = b;
        }
    }
}

// ---------------------------------------------------------------------------
// Kernel 1: x3 = silu_gate(xb @ w12t^T). 128x128 tile (=64 out cols), K=1024
// -> NT=32. Grid 1024x8 = 8192 blocks, 4 blocks/CU.
// ---------------------------------------------------------------------------
__global__ __launch_bounds__(256, 4)
void gate_gemm(const unsigned short* __restrict__ xb,
               const unsigned short* __restrict__ w12t,
               unsigned short* __restrict__ x3) {
    __shared__ unsigned short lds[20480];    // 40 KB
    const int tid = threadIdx.x;
    const int lane = tid & 63;
    const int wv = tid >> 6;
    const int wr = wv >> 1, wc = wv & 1;
    const int lhi = lane >> 4, llo = lane & 15;

    int bid = blockIdx.x;                    // 8192 blocks
    int wgid = (bid & 7) * 1024 + (bid >> 3);// bijective XCD chunks
    const int mt = wgid >> 3, nt = wgid & 7;

    f32x4 acc[4][4];
#pragma unroll
    for (int i = 0; i < 4; ++i)
#pragma unroll
        for (int j = 0; j < 4; ++j) acc[i][j] = (f32x4){0.f, 0.f, 0.f, 0.f};

    gemmC<32>(xb + (long)mt * 128 * 1024, w12t + (long)nt * 128 * 1024,
              1024, 1024, lds, acc, tid);

    // ---- epilogue: pair even/odd interleaved cols (gate/up), SiLU, repack -
    __syncthreads();
    // repack tile [128][72] ushorts (even lanes write; pitch 72 breaks banks)
#pragma unroll
    for (int i = 0; i < 4; ++i)
#pragma unroll
        for (int rr = 0; rr < 4; ++rr) {
            int R = wr * 64 + i * 16 + lhi * 4 + rr;
#pragma unroll
            for (int j = 0; j < 4; ++j) {
                float v = acc[i][j][rr];
                float p = __shfl_xor(v, 1, 64);
                float g = (lane & 1) ? p : v;
                float u = (lane & 1) ? v : p;
                float s = (g / (1.0f + __expf(-g))) * u;
                if (!(lane & 1))
                    lds[R * 72 + wc * 32 + j * 8 + (llo >> 1)] = f2bf(s);
            }
        }
    __syncthreads();
    // store: 128 rows x 64 ushorts = 1024 chunks of 16B, 4 per thread
    unsigned short* xg = x3 + (long)(mt * 128) * 512 + nt * 64;
#pragma unroll
    for (int i = 0; i < 4; ++i) {
        int c = i * 256 + tid;
        int row = c >> 3, ch = c & 7;
        *(bf16x8*)(xg + (long)row * 512 + ch * 8) = *(const bf16x8*)&lds[row * 72 + ch * 8];
    }
}

// ---------------------------------------------------------------------------
// Kernel 2: out = x3 @ w3t (M x 1024 fp32). 128x128 tile, K=512 -> NT=16.
// Grid 1024x8 = 8192 blocks, 4 blocks/CU.
// ---------------------------------------------------------------------------
__global__ __launch_bounds__(256, 4)
void down_gemm(const unsigned short* __restrict__ x3,
               const unsigned short* __restrict__ w3t,
               float* __restrict__ out) {
    __shared__ unsigned short lds[20480];
    const int tid = threadIdx.x;
    const int lane = tid & 63;
    const int wv = tid >> 6;
    const int wr = wv >> 1, wc = wv & 1;
    const int lhi = lane >> 4, llo = lane & 15;

    int bid = blockIdx.x;                    // 8192 blocks
    int wgid = (bid & 7) * 1024 + (bid >> 3);
    const int mt = wgid >> 3, nt = wgid & 7;

    f32x4 acc[4][4];
#pragma unroll
    for (int i = 0; i < 4; ++i)
#pragma unroll
        for (int j = 0; j < 4; ++j) acc[i][j] = (f32x4){0.f, 0.f, 0.f, 0.f};

    gemmC<16>(x3 + (long)mt * 128 * 512, w3t + (long)nt * 128 * 512,
              512, 512, lds, acc, tid);

    float* op = out + (long)(mt * 128) * 1024 + nt * 128;
#pragma unroll
    for (int i = 0; i < 4; ++i)
#pragma unroll
        for (int rr = 0; rr < 4; ++rr) {
            int R = wr * 64 + i * 16 + lhi * 4 + rr;
#pragma unroll
            for (int j = 0; j < 4; ++j)
                op[(long)R * 1024 + wc * 64 + j * 16 + llo] = acc[i][j][rr];
        }
}

// ---------------------------------------------------------------------------
extern "C" void kernel_launch(void* const* d_in, const int* in_sizes, int n_in,
                              void* d_out, int out_size, void* d_ws, size_t ws_size,
                              hipStream_t stream) {
    const float* x  = (const float*)d_in[0];
    const float* w0 = (const float*)d_in[1];
    const float* w1 = (const float*)d_in[2];
    const float* w2 = (const float*)d_in[3];
    const float* w3 = (const float*)d_in[4];
    float* out = (float*)d_out;

    unsigned short* w12t = (unsigned short*)d_ws;           // 2MB
    unsigned short* w3t  = w12t + 1024 * 1024;              // 1MB
    unsigned short* x3   = w3t + 1024 * 512;                // 128MB
    unsigned short* xb   = x3 + (size_t)131072 * 512;       // 256MB

    prep_w<<<dim3(6144), dim3(256), 0, stream>>>(w0, w1, w2, w3, w12t, w3t);
    prep_x<<<dim3(2048), dim3(256), 0, stream>>>(x, xb);
    gate_gemm<<<dim3(8192), dim3(256), 0, stream>>>(xb, w12t, x3);
    down_gemm<<<dim3(8192), dim3(256), 0, stream>>>(x3, w3t, out);
}

// Round 15
// 701.438 us; speedup vs baseline: 1.0369x; 1.0369x over previous
//
#include <hip/hip_runtime.h>
#include <cstdint>

typedef __attribute__((ext_vector_type(4))) float f32x4;
typedef __attribute__((ext_vector_type(8))) short bf16x8;
typedef __attribute__((ext_vector_type(4))) short bf16x4;

#define DEV static __device__ __forceinline__

// round-to-nearest-even f32 -> bf16 (bit pattern)
DEV unsigned short f2bf(float f) {
    union { float f; unsigned int u; } v; v.f = f;
    unsigned int u = v.u;
    return (unsigned short)((u + 0x7FFFu + ((u >> 16) & 1u)) >> 16);
}

// async global->LDS 16B per lane; LDS dest = wave-uniform base + lane*16
DEV void async_cp16(const void* g, void* l) {
    __builtin_amdgcn_global_load_lds(
        (const __attribute__((address_space(1))) unsigned int*)g,
        (__attribute__((address_space(3))) unsigned int*)l,
        16, 0, 0);
}

#define BAR __builtin_amdgcn_s_barrier();
#define SCB __builtin_amdgcn_sched_barrier(0);
#define LGKM0 asm volatile("s_waitcnt lgkmcnt(0)");
#define P1 __builtin_amdgcn_s_setprio(1);
#define P0 __builtin_amdgcn_s_setprio(0);
#define VM0 asm volatile("s_waitcnt vmcnt(0)" ::: "memory");
#define VM2 asm volatile("s_waitcnt vmcnt(2)" ::: "memory");

// one-off staging for the prologue (address math paid once).
// 128x64 bf16 half-tile: 512 thr x 2 chunks of 16B; linear LDS dest,
// inverse-swizzled source (involution: slot ^= row&7).
DEV void stage_half(const unsigned short* __restrict__ g, long kofs,
                    unsigned short* l, int tid, int gpitch) {
#pragma unroll
    for (int i = 0; i < 2; ++i) {
        int c = i * 512 + tid;
        int row = c >> 3;
        int ss = (c & 7) ^ (row & 7);
        async_cp16(g + (long)row * gpitch + kofs + ss * 8,
                   l + (i * 512 + (tid & 448)) * 8);
    }
}

// incremental staging pointers: per-lane addresses computed ONCE, advanced
// by a constant (+128 elements = 2 K-tiles) per iteration -> no per-load
// 64-bit address rebuild in the loop (the m97-asm VALU parasite).
struct SP { const unsigned short* p0; const unsigned short* p1; };

DEV SP mk_sp(const unsigned short* __restrict__ g, long kofs, int tid, int gp) {
    int c0 = tid, r0 = c0 >> 3, s0 = (c0 & 7) ^ (r0 & 7);
    int c1 = 512 + tid, r1 = c1 >> 3, s1 = (c1 & 7) ^ (r1 & 7);
    SP s;
    s.p0 = g + (long)r0 * gp + kofs + s0 * 8;
    s.p1 = g + (long)r1 * gp + kofs + s1 * 8;
    return s;
}

DEV void stage_p(SP& s, unsigned short* l, int tid) {
    async_cp16(s.p0, l + (tid & 448) * 8);
    async_cp16(s.p1, l + (512 + (tid & 448)) * 8);
    s.p0 += 128; s.p1 += 128;
}

// ---------------------------------------------------------------------------
// 256x256 8-wave GEMM core (R8's proven 8-phase schedule; addressing
// VALU-stripped). BK=64, NT K-tiles (even), dbuf'd 128KB LDS.
// LDS bytes: A(buf,h) = buf*32768 + wr-half, B at +65536. All ds_reads are
// 4 precomputed per-lane byte bases (A/B x kq0/kq1) + compile-time
// immediates (i*2048, j*2048, +8192 rows64, +4096 bf1, +32768 buf1) -- every
// immediate < 64KB so they fold into the ds_read offset field.
// Sync/vmcnt ledger identical to R8 (verified passing).
// ---------------------------------------------------------------------------
template <int NT>
DEV void gemm256(const unsigned short* __restrict__ gA,
                 const unsigned short* __restrict__ gB,
                 const int gpitch, unsigned short* lds,
                 f32x4 (&acc)[8][4], const int tid) {
    const int lane = tid & 63;
    const int wv = tid >> 6;
    const int wr = wv >> 2, wcq = wv & 3;
    const int lhi = lane >> 4, llo = lane & 15;
    const int hb = wcq >> 1;
    const int brq = wcq & 1;

    const char* lb = (const char*)lds;
    const int swz0 = (lhi ^ (llo & 7)) * 16;
    const int swz1 = ((4 + lhi) ^ (llo & 7)) * 16;
    const int aA0 = wr * 16384 + llo * 128 + swz0;           // A, kq=0
    const int aA1 = wr * 16384 + llo * 128 + swz1;           // A, kq=1
    const int aB0 = 65536 + hb * 16384 + brq * 8192 + llo * 128 + swz0;
    const int aB1 = 65536 + hb * 16384 + brq * 8192 + llo * 128 + swz1;

#define MG(AF, BF, RI0, CJ0)                                                  \
    _Pragma("unroll") for (int kq = 0; kq < 2; ++kq)                          \
    _Pragma("unroll") for (int i = 0; i < 4; ++i)                             \
    _Pragma("unroll") for (int j = 0; j < 2; ++j)                             \
        acc[RI0 + i][CJ0 + j] = __builtin_amdgcn_mfma_f32_16x16x32_bf16(      \
            AF[kq][i], BF[kq][j], acc[RI0 + i][CJ0 + j], 0, 0, 0);

#define LD8(OFF) (*(const bf16x8*)(lb + (OFF)))
#define RD_AF0(CO) _Pragma("unroll") for (int i = 0; i < 4; ++i) {            \
        af0[0][i] = LD8(aA0 + (CO) + i * 2048);                               \
        af0[1][i] = LD8(aA1 + (CO) + i * 2048); }
#define RD_AF1(CO) _Pragma("unroll") for (int i = 0; i < 4; ++i) {            \
        af1[0][i] = LD8(aA0 + (CO) + 8192 + i * 2048);                        \
        af1[1][i] = LD8(aA1 + (CO) + 8192 + i * 2048); }
#define RD_BF0(CO) _Pragma("unroll") for (int j = 0; j < 2; ++j) {            \
        bf0[0][j] = LD8(aB0 + (CO) + j * 2048);                               \
        bf0[1][j] = LD8(aB1 + (CO) + j * 2048); }
#define RD_BF1(CO) _Pragma("unroll") for (int j = 0; j < 2; ++j) {            \
        bf1[0][j] = LD8(aB0 + (CO) + 4096 + j * 2048);                        \
        bf1[1][j] = LD8(aB1 + (CO) + 4096 + j * 2048); }

    // prologue: K-tile 0 (8 loads) + tile 1's A[h0] (2 loads), wait tile 0
    stage_half(gA, 0, lds + 0, tid, gpitch);                       // A[0,h0]
    stage_half(gA + (long)128 * gpitch, 0, lds + 8192, tid, gpitch); // A[0,h1]
    stage_half(gB, 0, lds + 32768, tid, gpitch);                   // B[0,h0]
    stage_half(gB + (long)128 * gpitch, 0, lds + 40960, tid, gpitch); // B[0,h1]
    if (NT > 1) {
        stage_half(gA, 64, lds + 16384, tid, gpitch);              // A[1,h0]
        VM2
    } else {
        VM0
    }
    BAR SCB

    // role pointers (first-use K offsets; advance +128/iter inside stage_p)
    SP sA1o = mk_sp(gA + (long)128 * gpitch, 64, tid, gpitch);   // ph0 -> 24576
    SP sB0o = mk_sp(gB, 64, tid, gpitch);                        // ph1 -> 49152
    SP sB1o = mk_sp(gB + (long)128 * gpitch, 64, tid, gpitch);   // ph2 -> 57344
    SP sA0e = mk_sp(gA, 128, tid, gpitch);                       // ph3 -> 0
    SP sA1e = mk_sp(gA + (long)128 * gpitch, 128, tid, gpitch);  // ph4 -> 8192
    SP sB0e = mk_sp(gB, 128, tid, gpitch);                       // ph5 -> 32768
    SP sB1e = mk_sp(gB + (long)128 * gpitch, 128, tid, gpitch);  // ph6 -> 40960
    SP sA0o = mk_sp(gA, 192, tid, gpitch);                       // ph7 -> 16384

    bf16x8 af0[2][4], af1[2][4], bf0[2][2], bf1[2][2];

    for (int it = 0; it < NT / 2; ++it) {
        const bool pf = (it + 1 < NT / 2);

        // ================= tile E (buf0, CO=0) =================
        RD_AF0(0) RD_BF0(0)
        stage_p(sA1o, lds + 24576, tid);
        BAR LGKM0 SCB
        P1 MG(af0, bf0, 0, 0) P0
        BAR
        RD_BF1(0)
        stage_p(sB0o, lds + 49152, tid);
        BAR LGKM0 SCB
        P1 MG(af0, bf1, 0, 2) P0
        BAR
        RD_AF1(0)
        stage_p(sB1o, lds + 57344, tid);
        BAR LGKM0 SCB
        P1 MG(af1, bf0, 4, 0) P0
        BAR
        if (pf) stage_p(sA0e, lds + 0, tid);
        BAR
        P1 MG(af1, bf1, 4, 2) P0
        if (pf) { VM2 } else { VM0 }
        BAR SCB

        // ================= tile O (buf1, CO=32768) =================
        RD_AF0(32768) RD_BF0(32768)
        if (pf) stage_p(sA1e, lds + 8192, tid);
        BAR LGKM0 SCB
        P1 MG(af0, bf0, 0, 0) P0
        BAR
        RD_BF1(32768)
        if (pf) stage_p(sB0e, lds + 32768, tid);
        BAR LGKM0 SCB
        P1 MG(af0, bf1, 0, 2) P0
        BAR
        RD_AF1(32768)
        if (pf) stage_p(sB1e, lds + 40960, tid);
        BAR LGKM0 SCB
        P1 MG(af1, bf0, 4, 0) P0
        BAR
        if (pf) stage_p(sA0o, lds + 16384, tid);
        BAR
        P1 MG(af1, bf1, 4, 2) P0
        if (pf) { VM2 }
        BAR SCB
    }
#undef MG
#undef LD8
#undef RD_AF0
#undef RD_AF1
#undef RD_BF0
#undef RD_BF1
}

// ---------------------------------------------------------------------------
// Kernel 0: weight prep.
//  w12t[n][k]: n even -> bf16(w0[k]*w1[k][n/2]), n odd -> bf16(w0[k]*w2[k][n/2])
//  w3t[j][n] = bf16(w3[n][j])   (1024 x 512, n contiguous)
// ---------------------------------------------------------------------------
__global__ void prep_w(const float* __restrict__ w0, const float* __restrict__ w1,
                       const float* __restrict__ w2, const float* __restrict__ w3,
                       unsigned short* __restrict__ w12t, unsigned short* __restrict__ w3t) {
    int t = blockIdx.x * 256 + threadIdx.x;
    if (t < 1048576) {
        int n = t >> 10, k = t & 1023;
        const float* src = (n & 1) ? w2 : w1;
        w12t[t] = f2bf(w0[k] * src[k * 512 + (n >> 1)]);
    } else {
        int idx = t - 1048576;
        int j = idx >> 9, n = idx & 511;
        w3t[idx] = f2bf(w3[n * 1024 + j]);
    }
}

// ---------------------------------------------------------------------------
// Kernel 0b: RMSNorm fold. xb[row][k] = bf16(x[row][k] * rsqrt(mean(x^2)))
// ---------------------------------------------------------------------------
__global__ __launch_bounds__(256)
void prep_x(const float* __restrict__ x, unsigned short* __restrict__ xb) {
    const int wv = threadIdx.x >> 6, lane = threadIdx.x & 63;
    const int stride = gridDim.x * 4;
    for (int row = blockIdx.x * 4 + wv; row < 131072; row += stride) {
        const float* xr = x + (long)row * 1024;
        f32x4 v[4];
        float s = 0.f;
#pragma unroll
        for (int c = 0; c < 4; ++c) {
            v[c] = *(const f32x4*)(xr + c * 256 + lane * 4);
            s += v[c].x * v[c].x + v[c].y * v[c].y + v[c].z * v[c].z + v[c].w * v[c].w;
        }
#pragma unroll
        for (int off = 32; off > 0; off >>= 1) s += __shfl_xor(s, off, 64);
        float l = rsqrtf(s * (1.0f / 1024.0f));
        unsigned short* xo = xb + (long)row * 1024;
#pragma unroll
        for (int c = 0; c < 4; ++c) {
            bf16x4 b;
            b.x = (short)f2bf(v[c].x * l);
            b.y = (short)f2bf(v[c].y * l);
            b.z = (short)f2bf(v[c].z * l);
            b.w = (short)f2bf(v[c].w * l);
            *(bf16x4*)(xo + c * 256 + lane * 4) = b;
        }
    }
}

// ---------------------------------------------------------------------------
// Kernel 1: x3 = silu_gate(xb @ w12t^T). 256x256 tile, K=1024 -> 16 K-tiles.
// ---------------------------------------------------------------------------
__global__ __launch_bounds__(512, 2)
void gate_gemm(const unsigned short* __restrict__ xb,
               const unsigned short* __restrict__ w12t,
               unsigned short* __restrict__ x3) {
    __shared__ unsigned short lds[65536];    // 128 KB
    const int tid = threadIdx.x;
    const int lane = tid & 63;
    const int wv = tid >> 6;
    const int wr = wv >> 2, wcq = wv & 3;
    const int lhi = lane >> 4, llo = lane & 15;

    int bid = blockIdx.x;                    // 2048 blocks
    int wgid = (bid & 7) * 256 + (bid >> 3); // bijective XCD chunks
    const int mt = wgid >> 2, nt = wgid & 3;

    f32x4 acc[8][4];
#pragma unroll
    for (int i = 0; i < 8; ++i)
#pragma unroll
        for (int j = 0; j < 4; ++j) acc[i][j] = (f32x4){0.f, 0.f, 0.f, 0.f};

    gemm256<16>(xb + (long)mt * 256 * 1024, w12t + (long)nt * 256 * 1024,
                1024, lds, acc, tid);

    // ---- epilogue: pair even/odd interleaved cols (gate/up), SiLU, repack --
    // repack tile [256][136] ushorts (272B pitch)
#pragma unroll
    for (int ri = 0; ri < 8; ++ri)
#pragma unroll
        for (int rr = 0; rr < 4; ++rr) {
            int R = wr * 128 + ri * 16 + lhi * 4 + rr;
#pragma unroll
            for (int cj = 0; cj < 4; ++cj) {
                float v = acc[ri][cj][rr];
                float p = __shfl_xor(v, 1, 64);
                float g = (lane & 1) ? p : v;
                float u = (lane & 1) ? v : p;
                float s = (g / (1.0f + __expf(-g))) * u;
                if (!(lane & 1))
                    lds[R * 136 + wcq * 32 + cj * 8 + (llo >> 1)] = f2bf(s);
            }
        }
    __syncthreads();
    unsigned short* xg = x3 + (long)(mt * 256) * 512 + nt * 128;
#pragma unroll
    for (int i = 0; i < 8; ++i) {
        int c = i * 512 + tid;               // 4096 chunks of 16B
        int row = c >> 4, ch = c & 15;
        *(bf16x8*)(xg + (long)row * 512 + ch * 8) = *(const bf16x8*)&lds[row * 136 + ch * 8];
    }
}

// ---------------------------------------------------------------------------
// Kernel 2: out = x3 @ w3t (M x 1024 fp32). 256x256 tile, K=512 -> 8 K-tiles.
// ---------------------------------------------------------------------------
__global__ __launch_bounds__(512, 2)
void down_gemm(const unsigned short* __restrict__ x3,
               const unsigned short* __restrict__ w3t,
               float* __restrict__ out) {
    __shared__ unsigned short lds[65536];
    const int tid = threadIdx.x;
    const int lane = tid & 63;
    const int wv = tid >> 6;
    const int wr = wv >> 2, wcq = wv & 3;
    const int lhi = lane >> 4, llo = lane & 15;

    int bid = blockIdx.x;                    // 2048 blocks
    int wgid = (bid & 7) * 256 + (bid >> 3);
    const int mt = wgid >> 2, nt = wgid & 3;

    f32x4 acc[8][4];
#pragma unroll
    for (int i = 0; i < 8; ++i)
#pragma unroll
        for (int j = 0; j < 4; ++j) acc[i][j] = (f32x4){0.f, 0.f, 0.f, 0.f};

    gemm256<8>(x3 + (long)mt * 256 * 512, w3t + (long)nt * 256 * 512,
               512, lds, acc, tid);

    float* op = out + (long)(mt * 256) * 1024 + nt * 256;
#pragma unroll
    for (int ri = 0; ri < 8; ++ri)
#pragma unroll
        for (int rr = 0; rr < 4; ++rr) {
            int R = wr * 128 + ri * 16 + lhi * 4 + rr;
#pragma unroll
            for (int cj = 0; cj < 4; ++cj)
                op[(long)R * 1024 + wcq * 64 + cj * 16 + llo] = acc[ri][cj][rr];
        }
}

// ---------------------------------------------------------------------------
extern "C" void kernel_launch(void* const* d_in, const int* in_sizes, int n_in,
                              void* d_out, int out_size, void* d_ws, size_t ws_size,
                              hipStream_t stream) {
    const float* x  = (const float*)d_in[0];
    const float* w0 = (const float*)d_in[1];
    const float* w1 = (const float*)d_in[2];
    const float* w2 = (const float*)d_in[3];
    const float* w3 = (const float*)d_in[4];
    float* out = (float*)d_out;

    unsigned short* w12t = (unsigned short*)d_ws;           // 2MB
    unsigned short* w3t  = w12t + 1024 * 1024;              // 1MB
    unsigned short* x3   = w3t + 1024 * 512;                // 128MB
    unsigned short* xb   = x3 + (size_t)131072 * 512;       // 256MB

    prep_w<<<dim3(6144), dim3(256), 0, stream>>>(w0, w1, w2, w3, w12t, w3t);
    prep_x<<<dim3(2048), dim3(256), 0, stream>>>(x, xb);
    gate_gemm<<<dim3(2048), dim3(512), 0, stream>>>(xb, w12t, x3);
    down_gemm<<<dim3(2048), dim3(512), 0, stream>>>(x3, w3t, out);
}